// Round 3
// baseline (144.721 us; speedup 1.0000x reference)
//
#include <hip/hip_runtime.h>

// GaussianRecuModel: B=512 batches, T=8192-step affine recurrence on 2-state x.
//   x_{t+1} = Mt x_t + bt,  Mt = I + dt*A - dt*(xic_t C),  bt = xic_t dy_t
//   out_t   = dt * C x_t   (state BEFORE update)
//
// Single-pass fused kernel, one 1024-thread block per batch, 8 steps/thread
// in registers. R4: all global accesses wave-coalesced float4; LDS slice
// transposes between coalesced order and 8-contiguous-steps-per-thread order.
// R5/R6: per-wave slice cut 4 KiB -> 2 KiB (block LDS 64 KiB -> 32 KiB) so
// TWO blocks can be co-resident per CU (64 KiB/block observed ~1 block/CU,
// 35% occupancy). Transposes run in twice as many owner-rounds; identical
// XOR-swizzle bank-conflict-free patterns. R6: launch_bounds back to (NT,4)
// (known-good from R0; VGPR=52 <= 64 so 2 blocks/CU reachable without the
// tighter directive, which is the only untested build-level delta from the
// last passing kernel).

#define B_   512
#define T_   8192
#define LPT  8                  // steps per thread
#define NT   1024               // threads per block (16 waves)
static_assert(NT * LPT == T_, "one block covers one batch");

#define SLICE_F4 128            // 2 KiB per wave

struct Aff { float m00, m01, m10, m11, v0, v1; };

__device__ __forceinline__ Aff aff_compose(const Aff& L, const Aff& E) {
    Aff r;
    r.m00 = L.m00*E.m00 + L.m01*E.m10;
    r.m01 = L.m00*E.m01 + L.m01*E.m11;
    r.m10 = L.m10*E.m00 + L.m11*E.m10;
    r.m11 = L.m10*E.m01 + L.m11*E.m11;
    r.v0  = L.m00*E.v0  + L.m01*E.v1 + L.v0;
    r.v1  = L.m10*E.v0  + L.m11*E.v1 + L.v1;
    return r;
}

__device__ __forceinline__ Aff aff_identity() {
    Aff r; r.m00 = 1.f; r.m01 = 0.f; r.m10 = 0.f; r.m11 = 1.f; r.v0 = 0.f; r.v1 = 0.f;
    return r;
}

__global__ __launch_bounds__(NT, 4) void grm_fused(
    const float* __restrict__ xic, const float* __restrict__ dy,
    const float* __restrict__ Aptr, const float* __restrict__ Cptr,
    float4* __restrict__ out4)
{
    // 16 waves x 128 float4 (2 KiB) = 32 KiB -> 2 blocks/CU possible.
    // Each wave uses ONLY its slice except the wtot exchange (barrier-guarded).
    __shared__ float4 lds4[16 * SLICE_F4];

    const int b    = blockIdx.x;
    const int tid  = threadIdx.x;
    const int lane = tid & 63;
    const int wave = tid >> 6;

    float4* slice = lds4 + wave * SLICE_F4;

    const float DT = 1e-3f;
    const float cd00 = Cptr[0]*DT, cd01 = Cptr[1]*DT;
    const float cd10 = Cptr[2]*DT, cd11 = Cptr[3]*DT;
    const float i00 = 1.0f + Aptr[0]*DT, i01 = Aptr[1]*DT;
    const float i10 = Aptr[2]*DT,        i11 = 1.0f + Aptr[3]*DT;

    // global bases in float4 units; wave covers 512 steps
    const int wbase = b * T_ + wave * 512;                 // step index
    const float4* xw = (const float4*)xic + wbase;          // 512 float4 / wave
    const float4* dw = (const float4*)dy  + (wbase >> 1);   // 256 float4 / wave
    float4*       ow = out4 + (wbase >> 1);                 // 256 float4 / wave

    // ---- issue ALL global loads, fully coalesced (lane-contiguous) ----
    float4 t[8], u[4];
    #pragma unroll
    for (int j = 0; j < 8; ++j) t[j] = xw[j*64 + lane];
    #pragma unroll
    for (int j = 0; j < 4; ++j) u[j] = dw[j*64 + lane];

    // ---- xic transpose: four owner-rounds through the 2 KiB slice ----
    // Round r covers f in [128r, 128r+128); owner o = f>>3, rel = o&15,
    // slot = f&7 = lane&7, swizzled addr = rel*8 + (slot ^ (rel&7)).
    // Writes: 8-lane groups have fixed rel, slot 0..7 -> all 8 bank-groups,
    // conflict-free. Reads: 16 active lanes, 2-way max (free).
    // Same-wave DS ordering makes cross-round slice reuse safe (no barrier).
    float4 a[LPT];
    #pragma unroll
    for (int r = 0; r < 4; ++r) {
        #pragma unroll
        for (int jj = 0; jj < 2; ++jj) {
            int j = 2*r + jj;
            int f = j*64 + lane;
            int rel = (f >> 3) & 15;
            slice[rel*8 + ((lane & 7) ^ (rel & 7))] = t[j];
        }
        if ((lane >> 4) == r) {
            int rel = lane & 15;
            #pragma unroll
            for (int s = 0; s < LPT; ++s)
                a[s] = slice[rel*8 + (s ^ (rel & 7))];
        }
    }

    // ---- dy transpose: two owner-rounds. o = f>>2, rel = o&31, slot = f&3 ----
    float4 d[4];
    #pragma unroll
    for (int r = 0; r < 2; ++r) {
        #pragma unroll
        for (int jj = 0; jj < 2; ++jj) {
            int j = 2*r + jj;
            int f = j*64 + lane;
            int rel = (f >> 2) & 31;
            slice[rel*4 + ((lane & 3) ^ (rel & 3))] = u[j];
        }
        if ((lane >> 5) == r) {
            int rel = lane & 31;
            #pragma unroll
            for (int s = 0; s < 4; ++s)
                d[s] = slice[rel*4 + (s ^ (rel & 3))];
        }
    }

#define STEP_MAP(i, S)                                                  \
    {                                                                   \
        const float4 x4 = a[i];                                         \
        const float dyx = ((i)&1) ? d[(i)>>1].z : d[(i)>>1].x;          \
        const float dyy = ((i)&1) ? d[(i)>>1].w : d[(i)>>1].y;          \
        (S).m00 = i00 - (x4.x*cd00 + x4.y*cd10);                        \
        (S).m01 = i01 - (x4.x*cd01 + x4.y*cd11);                        \
        (S).m10 = i10 - (x4.z*cd00 + x4.w*cd10);                        \
        (S).m11 = i11 - (x4.z*cd01 + x4.w*cd11);                        \
        (S).v0  = x4.x*dyx + x4.y*dyy;                                  \
        (S).v1  = x4.z*dyx + x4.w*dyy;                                  \
    }

    // ---- thread-local compose: P = T7 o ... o T0 ----
    Aff P;
    STEP_MAP(0, P);
    #pragma unroll
    for (int i = 1; i < LPT; ++i) { Aff s; STEP_MAP(i, s); P = aff_compose(s, P); }

    // ---- wave Kogge-Stone inclusive scan (64 lanes) ----
    Aff S = P;
    #pragma unroll
    for (int sh = 1; sh < 64; sh <<= 1) {
        Aff q;
        q.m00 = __shfl_up(S.m00, sh); q.m01 = __shfl_up(S.m01, sh);
        q.m10 = __shfl_up(S.m10, sh); q.m11 = __shfl_up(S.m11, sh);
        q.v0  = __shfl_up(S.v0,  sh); q.v1  = __shfl_up(S.v1,  sh);
        if (lane >= sh) S = aff_compose(S, q);
    }

    // ---- wave totals -> own slice header (slice free: a,d in regs) ----
    if (lane == 63) {
        float* h = (float*)slice;
        h[0] = S.m00; h[1] = S.m01; h[2] = S.m10; h[3] = S.m11;
        h[4] = S.v0;  h[5] = S.v1;
    }
    __syncthreads();

    // ---- wave-exclusive prefix (serial over earlier waves' headers) ----
    Aff Ew = aff_identity();
    for (int w = 0; w < wave; ++w) {
        const float* h = (const float*)(lds4 + w * SLICE_F4);
        Aff t2;
        t2.m00 = h[0]; t2.m01 = h[1]; t2.m10 = h[2]; t2.m11 = h[3];
        t2.v0  = h[4]; t2.v1  = h[5];
        Ew = aff_compose(t2, Ew);
    }
    __syncthreads();   // headers consumed; slices reusable for out staging

    // ---- lane-exclusive prefix within wave ----
    Aff El;
    El.m00 = __shfl_up(S.m00, 1); El.m01 = __shfl_up(S.m01, 1);
    El.m10 = __shfl_up(S.m10, 1); El.m11 = __shfl_up(S.m11, 1);
    El.v0  = __shfl_up(S.v0,  1); El.v1  = __shfl_up(S.v1,  1);
    if (lane == 0) El = aff_identity();

    Aff E = aff_compose(El, Ew);
    float x0 = E.m00 + E.v0;
    float x1 = E.m10 + E.v1;

    // ---- replay from registers ----
    float4 o4[4];
    #pragma unroll
    for (int i = 0; i < LPT; ++i) {
        float oxx = cd00*x0 + cd01*x1;
        float oyy = cd10*x0 + cd11*x1;
        if (i & 1) { o4[i>>1].z = oxx; o4[i>>1].w = oyy; }
        else       { o4[i>>1].x = oxx; o4[i>>1].y = oyy; }
        Aff s; STEP_MAP(i, s);
        float nx0 = s.m00*x0 + s.m01*x1 + s.v0;
        float nx1 = s.m10*x0 + s.m11*x1 + s.v1;
        x0 = nx0; x1 = nx1;
    }
#undef STEP_MAP

    // ---- out transpose: own-order -> coalesced stores, two rounds ----
    #pragma unroll
    for (int r = 0; r < 2; ++r) {
        if ((lane >> 5) == r) {
            int rel = lane & 31;
            #pragma unroll
            for (int s = 0; s < 4; ++s)
                slice[rel*4 + (s ^ (rel & 3))] = o4[s];
        }
        #pragma unroll
        for (int jj = 0; jj < 2; ++jj) {
            int j = 2*r + jj;
            int f = j*64 + lane;
            int rel = (f >> 2) & 31;
            ow[f] = slice[rel*4 + ((lane & 3) ^ (rel & 3))];
        }
    }
}

extern "C" void kernel_launch(void* const* d_in, const int* in_sizes, int n_in,
                              void* d_out, int out_size, void* d_ws, size_t ws_size,
                              hipStream_t stream) {
    const float* xic  = (const float*)d_in[0];   // [B,T,2,2]
    const float* dy   = (const float*)d_in[1];   // [B,T,2]
    const float* Aptr = (const float*)d_in[2];   // [2,2]
    const float* Cptr = (const float*)d_in[3];   // [2,2]
    float4* out = (float4*)d_out;                // [B,T,2]

    grm_fused<<<B_, NT, 0, stream>>>(xic, dy, Aptr, Cptr, out);
}